// Round 1
// baseline (979.256 us; speedup 1.0000x reference)
//
#include <hip/hip_runtime.h>

// Problem: out[b,n,o] = sum_k x[b,n,k] * weight[y[b],k,o] + bias[y[b],o]
// B=1024, N=64, K=1152, O=128, fp32.
// One workgroup per sample b. Block tile = 64x128, K-step 32.
// 128 threads (2 waves), each computes an 8x8 micro-tile (64 acc VGPRs).

constexpr int Bn = 1024;
constexpr int Nn = 64;
constexpr int Kn = 1152;
constexpr int On = 128;
constexpr int KB = 32;
constexpr int NTHREADS = 128;

__global__ __launch_bounds__(NTHREADS, 2)
void ada_gemm_f32(const float* __restrict__ x,
                  const int* __restrict__ y,
                  const float* __restrict__ w,
                  const float* __restrict__ bias,
                  float* __restrict__ out)
{
    // As padded +1: compute-read bank = (row + k) % 32 -> conflict-free
    // (4 row-groups {0,8,16,24} x 16-lane broadcast).
    __shared__ float As[Nn][KB + 1];   // 64 x 33 = 8448 B
    __shared__ float Bs[KB][On];       // 32 x 128 = 16384 B

    const int b   = blockIdx.x;
    const int tid = threadIdx.x;
    const int cls = y[b];

    const float* __restrict__ xb = x + (size_t)b * Nn * Kn;
    const float* __restrict__ wb = w + (size_t)cls * Kn * On;

    const int rg = tid >> 4;   // 0..7  row group
    const int cg = tid & 15;   // 0..15 col group
    const int r0 = rg * 8;     // 8 rows per thread
    const int c0 = cg * 4;     // cols c0..c0+3 and c0+64..c0+67

    float acc[8][8];
    #pragma unroll
    for (int i = 0; i < 8; ++i)
        #pragma unroll
        for (int j = 0; j < 8; ++j)
            acc[i][j] = 0.0f;

    for (int k0 = 0; k0 < Kn; k0 += KB) {
        // ---- stage A tile: 64 rows x 32 k = 512 float4, 4 per thread ----
        #pragma unroll
        for (int i = 0; i < 4; ++i) {
            const int f  = tid + i * NTHREADS;   // 0..511
            const int n  = f >> 3;               // row 0..63
            const int k4 = f & 7;                // float4 index along k
            const float4 v = *reinterpret_cast<const float4*>(xb + n * Kn + k0 + k4 * 4);
            As[n][k4 * 4 + 0] = v.x;
            As[n][k4 * 4 + 1] = v.y;
            As[n][k4 * 4 + 2] = v.z;
            As[n][k4 * 4 + 3] = v.w;
        }
        // ---- stage B tile: 32 k-rows x 128 cols = 1024 float4, 8 per thread ----
        #pragma unroll
        for (int i = 0; i < 8; ++i) {
            const int f  = tid + i * NTHREADS;   // 0..1023
            const int kr = f >> 5;               // k-row 0..31
            const int c4 = f & 31;               // float4 col index
            const float4 v = *reinterpret_cast<const float4*>(wb + (size_t)(k0 + kr) * On + c4 * 4);
            *reinterpret_cast<float4*>(&Bs[kr][c4 * 4]) = v;
        }
        __syncthreads();

        // ---- compute ----
        #pragma unroll
        for (int k = 0; k < KB; ++k) {
            float a[8];
            #pragma unroll
            for (int i = 0; i < 8; ++i)
                a[i] = As[r0 + i][k];
            const float4 b0 = *reinterpret_cast<const float4*>(&Bs[k][c0]);
            const float4 b1 = *reinterpret_cast<const float4*>(&Bs[k][c0 + 64]);
            const float bb[8] = {b0.x, b0.y, b0.z, b0.w, b1.x, b1.y, b1.z, b1.w};
            #pragma unroll
            for (int i = 0; i < 8; ++i)
                #pragma unroll
                for (int j = 0; j < 8; ++j)
                    acc[i][j] = fmaf(a[i], bb[j], acc[i][j]);
        }
        __syncthreads();
    }

    // ---- epilogue: add bias, store ----
    const float4 bi0 = *reinterpret_cast<const float4*>(bias + (size_t)cls * On + c0);
    const float4 bi1 = *reinterpret_cast<const float4*>(bias + (size_t)cls * On + c0 + 64);
    float* __restrict__ ob = out + (size_t)b * Nn * On;
    #pragma unroll
    for (int i = 0; i < 8; ++i) {
        float4 o0, o1;
        o0.x = acc[i][0] + bi0.x;
        o0.y = acc[i][1] + bi0.y;
        o0.z = acc[i][2] + bi0.z;
        o0.w = acc[i][3] + bi0.w;
        o1.x = acc[i][4] + bi1.x;
        o1.y = acc[i][5] + bi1.y;
        o1.z = acc[i][6] + bi1.z;
        o1.w = acc[i][7] + bi1.w;
        *reinterpret_cast<float4*>(ob + (r0 + i) * On + c0)      = o0;
        *reinterpret_cast<float4*>(ob + (r0 + i) * On + c0 + 64) = o1;
    }
}

extern "C" void kernel_launch(void* const* d_in, const int* in_sizes, int n_in,
                              void* d_out, int out_size, void* d_ws, size_t ws_size,
                              hipStream_t stream) {
    const float* x    = (const float*)d_in[0];
    const int*   y    = (const int*)d_in[1];
    const float* w    = (const float*)d_in[2];
    const float* bias = (const float*)d_in[3];
    float* out = (float*)d_out;

    ada_gemm_f32<<<dim3(Bn), dim3(NTHREADS), 0, stream>>>(x, y, w, bias, out);
}

// Round 2
// 934.306 us; speedup vs baseline: 1.0481x; 1.0481x over previous
//
#include <hip/hip_runtime.h>

// out[b,n,o] = sum_k x[b,n,k] * w[y[b],k,o] + bias[y[b],o]
// B=1024 samples, N=64 rows, K=1152, O=128, fp32 in/out.
//
// Strategy: split-precision bf16 MFMA (hi/lo, 3 products, ~2^-16 rel err),
// one block per sample, 256 threads (4 waves, 2x2 wave grid, 32x64 per wave),
// K-step 32 (= one mfma_16x16x32 K), register-prefetch double buffering,
// class-sorted block order (counting sort pre-kernel) for weight L3 reuse.

typedef __bf16 bf16x8 __attribute__((ext_vector_type(8)));
typedef float f32x4 __attribute__((ext_vector_type(4)));

constexpr int Bn = 1024;
constexpr int Nn = 64;
constexpr int Kn = 1152;
constexpr int On = 128;
constexpr int KB = 32;
constexpr int NT = 256;
constexpr int NTILES = Kn / KB;   // 36
constexpr int RS = 36;            // ushort row stride (32 + 4 pad): 72 B rows

union FragU {
    bf16x8 v;
    uint2 u[2];
};
static_assert(sizeof(FragU) == 16, "frag size");

__device__ __forceinline__ void split2(float f, ushort& hi, ushort& lo) {
    // hi = truncate-to-bf16(f); lo = bf16(f - hi). Residual error ~2^-16*|f|.
    uint u = __float_as_uint(f);
    hi = (ushort)(u >> 16);
    float fl = f - __uint_as_float(u & 0xFFFF0000u);
    lo = (ushort)(__float_as_uint(fl) >> 16);
}

__device__ __forceinline__ uint pack2(ushort a, ushort b) {
    return (uint)a | ((uint)b << 16);
}

// ---------------- counting sort of samples by class ----------------
__global__ void sort_classes(const int* __restrict__ y, int* __restrict__ perm) {
    __shared__ int hist[1024];
    __shared__ int scan[1024];
    const int t = threadIdx.x;
    hist[t] = 0;
    __syncthreads();
    const int cls = y[t];
    atomicAdd(&hist[cls], 1);
    __syncthreads();
    const int v = hist[t];
    scan[t] = v;
    __syncthreads();
    // Hillis-Steele inclusive scan
    for (int off = 1; off < 1024; off <<= 1) {
        int u = (t >= off) ? scan[t - off] : 0;
        __syncthreads();
        scan[t] += u;
        __syncthreads();
    }
    hist[t] = scan[t] - v;   // exclusive prefix = class base offset
    __syncthreads();
    const int pos = atomicAdd(&hist[cls], 1);
    perm[pos] = t;
}

// ---------------- main GEMM ----------------
__global__ __launch_bounds__(NT, 3)
void ada_gemm_bf16s(const float* __restrict__ x, const int* __restrict__ y,
                    const float* __restrict__ w, const float* __restrict__ bias,
                    const int* __restrict__ perm, float* __restrict__ out) {
    __shared__ ushort As[2][Nn][RS];   // [plane][row][k]  9,216 B
    __shared__ ushort Bs[2][On][RS];   // [plane][o][k]   18,432 B (transposed w)

    const int tid = threadIdx.x;
    const int b   = perm[blockIdx.x];
    const int cls = y[b];
    const float* __restrict__ xb = x + (size_t)b * Nn * Kn;
    const float* __restrict__ wb = w + (size_t)cls * Kn * On;

    const int lane = tid & 63;
    const int wid  = tid >> 6;
    const int wr   = wid >> 1;        // wave row half (0..1): rows wr*32..+32
    const int wc   = wid & 1;         // wave col half (0..1): cols wc*64..+64
    const int l15  = lane & 15;
    const int kg   = lane >> 4;       // 0..3

    // staging maps
    const int an  = tid >> 3;         // A: row (i adds 32)
    const int ak4 = tid & 7;          // A: float4 index along k
    const int bkr = tid >> 5;         // B: k row (i adds 8)
    const int bo4 = (tid & 31) * 4;   // B: o base

    f32x4 acc[2][4];
    #pragma unroll
    for (int m = 0; m < 2; ++m)
        #pragma unroll
        for (int n = 0; n < 4; ++n)
            acc[m][n] = (f32x4)(0.0f);

    float4 pa[2], pb[4];
    #pragma unroll
    for (int i = 0; i < 2; ++i)
        pa[i] = *reinterpret_cast<const float4*>(xb + (size_t)(an + 32 * i) * Kn + ak4 * 4);
    #pragma unroll
    for (int i = 0; i < 4; ++i)
        pb[i] = *reinterpret_cast<const float4*>(wb + (size_t)(bkr + 8 * i) * On + bo4);

    for (int t = 0; t < NTILES; ++t) {
        __syncthreads();   // previous tile's compute done; LDS reusable

        // ---- convert + write A (contiguous b64 writes) ----
        #pragma unroll
        for (int i = 0; i < 2; ++i) {
            ushort h[4], l[4];
            split2(pa[i].x, h[0], l[0]);
            split2(pa[i].y, h[1], l[1]);
            split2(pa[i].z, h[2], l[2]);
            split2(pa[i].w, h[3], l[3]);
            uint2 ph; ph.x = pack2(h[0], h[1]); ph.y = pack2(h[2], h[3]);
            uint2 pl; pl.x = pack2(l[0], l[1]); pl.y = pack2(l[2], l[3]);
            *reinterpret_cast<uint2*>(&As[0][an + 32 * i][ak4 * 4]) = ph;
            *reinterpret_cast<uint2*>(&As[1][an + 32 * i][ak4 * 4]) = pl;
        }
        // ---- convert + transpose-scatter B ----
        #pragma unroll
        for (int i = 0; i < 4; ++i) {
            ushort h[4], l[4];
            split2(pb[i].x, h[0], l[0]);
            split2(pb[i].y, h[1], l[1]);
            split2(pb[i].z, h[2], l[2]);
            split2(pb[i].w, h[3], l[3]);
            const int kr = bkr + 8 * i;
            #pragma unroll
            for (int j = 0; j < 4; ++j) {
                Bs[0][bo4 + j][kr] = h[j];
                Bs[1][bo4 + j][kr] = l[j];
            }
        }
        // ---- prefetch next tile ----
        if (t + 1 < NTILES) {
            const int k0 = (t + 1) * KB;
            #pragma unroll
            for (int i = 0; i < 2; ++i)
                pa[i] = *reinterpret_cast<const float4*>(xb + (size_t)(an + 32 * i) * Kn + k0 + ak4 * 4);
            #pragma unroll
            for (int i = 0; i < 4; ++i)
                pb[i] = *reinterpret_cast<const float4*>(wb + (size_t)(k0 + bkr + 8 * i) * On + bo4);
        }
        __syncthreads();

        // ---- fragments ----
        FragU a[2][2];     // [plane][m]
        FragU bf[2][4];    // [plane][n]
        #pragma unroll
        for (int m = 0; m < 2; ++m) {
            const int row = wr * 32 + m * 16 + l15;
            a[0][m].u[0] = *reinterpret_cast<const uint2*>(&As[0][row][kg * 8]);
            a[0][m].u[1] = *reinterpret_cast<const uint2*>(&As[0][row][kg * 8 + 4]);
            a[1][m].u[0] = *reinterpret_cast<const uint2*>(&As[1][row][kg * 8]);
            a[1][m].u[1] = *reinterpret_cast<const uint2*>(&As[1][row][kg * 8 + 4]);
        }
        #pragma unroll
        for (int n = 0; n < 4; ++n) {
            const int o = wc * 64 + n * 16 + l15;
            bf[0][n].u[0] = *reinterpret_cast<const uint2*>(&Bs[0][o][kg * 8]);
            bf[0][n].u[1] = *reinterpret_cast<const uint2*>(&Bs[0][o][kg * 8 + 4]);
            bf[1][n].u[0] = *reinterpret_cast<const uint2*>(&Bs[1][o][kg * 8]);
            bf[1][n].u[1] = *reinterpret_cast<const uint2*>(&Bs[1][o][kg * 8 + 4]);
        }
        // ---- 3-product split MFMA, all into same acc ----
        #pragma unroll
        for (int m = 0; m < 2; ++m) {
            #pragma unroll
            for (int n = 0; n < 4; ++n) {
                acc[m][n] = __builtin_amdgcn_mfma_f32_16x16x32_bf16(a[0][m].v, bf[0][n].v, acc[m][n], 0, 0, 0);
                acc[m][n] = __builtin_amdgcn_mfma_f32_16x16x32_bf16(a[1][m].v, bf[0][n].v, acc[m][n], 0, 0, 0);
                acc[m][n] = __builtin_amdgcn_mfma_f32_16x16x32_bf16(a[0][m].v, bf[1][n].v, acc[m][n], 0, 0, 0);
            }
        }
    }

    // ---- epilogue: bias + store ----
    float* __restrict__ ob = out + (size_t)b * Nn * On;
    const float* __restrict__ bb = bias + (size_t)cls * On;
    #pragma unroll
    for (int n = 0; n < 4; ++n) {
        const int col = wc * 64 + n * 16 + l15;
        const float bv = bb[col];
        #pragma unroll
        for (int m = 0; m < 2; ++m) {
            const int row0 = wr * 32 + m * 16 + kg * 4;
            #pragma unroll
            for (int r = 0; r < 4; ++r)
                ob[(size_t)(row0 + r) * On + col] = acc[m][n][r] + bv;
        }
    }
}

extern "C" void kernel_launch(void* const* d_in, const int* in_sizes, int n_in,
                              void* d_out, int out_size, void* d_ws, size_t ws_size,
                              hipStream_t stream) {
    const float* x    = (const float*)d_in[0];
    const int*   y    = (const int*)d_in[1];
    const float* w    = (const float*)d_in[2];
    const float* bias = (const float*)d_in[3];
    float* out = (float*)d_out;
    int* perm  = (int*)d_ws;

    sort_classes<<<dim3(1), dim3(1024), 0, stream>>>(y, perm);
    ada_gemm_bf16s<<<dim3(Bn), dim3(NT), 0, stream>>>(x, y, w, bias, perm, out);
}